// Round 7
// baseline (247.912 us; speedup 1.0000x reference)
//
#include <hip/hip_runtime.h>
#include <hip/hip_bf16.h>

#define LSP 4096   // L = H*W
#define NC  256    // C
#define NH  128    // C/2
#define KB  32     // kv tile
#define QW  32     // q rows per wave (4 waves x 32 = 128 q / block)
#define SPLIT 8    // kv split factor
#define NTILE ((LSP / SPLIT) / KB)   // 16

typedef __attribute__((ext_vector_type(8))) short short8;
typedef __attribute__((ext_vector_type(4))) float f32x4;
typedef __attribute__((ext_vector_type(4))) unsigned int u32x4;
typedef __attribute__((ext_vector_type(2))) unsigned int u32x2;
typedef __hip_bfloat16 bf16;

#define MFMA16(a,b,c) __builtin_amdgcn_mfma_f32_16x16x32_bf16((a),(b),(c),0,0,0)

typedef __attribute__((address_space(1))) const void gas_t;
typedef __attribute__((address_space(3))) void las_t;
#define GLDS16(g, l) __builtin_amdgcn_global_load_lds((gas_t*)(g), (las_t*)(l), 16, 0, 0)

static __device__ __forceinline__ unsigned short f2bf(float f) {
  bf16 h = __float2bfloat16(f);
  return __builtin_bit_cast(unsigned short, h);
}
static __device__ __forceinline__ unsigned int packbf2(float a, float b) {
  return (unsigned int)f2bf(a) | ((unsigned int)f2bf(b) << 16);
}
static __device__ __forceinline__ float bf2f(unsigned short u) {
  return __builtin_bit_cast(float, (unsigned int)u << 16);
}
static __device__ __forceinline__ unsigned short bfu(bf16 h) {
  return __builtin_bit_cast(unsigned short, h);
}

// ---------- merged: weights->bf16 + bias concat (blocks 0..511) | SRM stats (512..1535)
__global__ __launch_bounds__(256) void k_pre(const float* __restrict__ a0,
    const float* __restrict__ a1, const float* __restrict__ a2,
    const float* __restrict__ a3, const float* __restrict__ tb,
    const float* __restrict__ pb, bf16* __restrict__ dst, float* __restrict__ bcat,
    const float* __restrict__ x, const float* __restrict__ cfc,
    float* __restrict__ gate) {
  int b = blockIdx.x;
  if (b < 512) {
    int i = b * 256 + threadIdx.x;
    int seg = i >> 15, off = i & 32767;
    const float* s = (seg == 0) ? a0 : (seg == 1) ? a1 : (seg == 2) ? a2 : a3;
    dst[i] = __float2bfloat16(s[off]);
    if (b == 0)
      bcat[threadIdx.x] = threadIdx.x < 128 ? tb[threadIdx.x] : pb[threadIdx.x - 128];
    return;
  }
  int nc = b - 512;   // n*C + c
  const float4* x4 = (const float4*)(x + (size_t)nc * LSP);
  float s = 0.f, q = 0.f;
  for (int i = threadIdx.x; i < LSP / 4; i += 256) {
    float4 v = x4[i];
    s += v.x + v.y + v.z + v.w;
    q += v.x * v.x + v.y * v.y + v.z * v.z + v.w * v.w;
  }
#pragma unroll
  for (int o = 32; o > 0; o >>= 1) { s += __shfl_xor(s, o); q += __shfl_xor(q, o); }
  __shared__ float rs[4], rq[4];
  int w = threadIdx.x >> 6;
  if ((threadIdx.x & 63) == 0) { rs[w] = s; rq[w] = q; }
  __syncthreads();
  if (threadIdx.x == 0) {
    float S = rs[0] + rs[1] + rs[2] + rs[3];
    float Q = rq[0] + rq[1] + rq[2] + rq[3];
    float mean = S / (float)LSP;
    float var = (Q - S * S / (float)LSP) / (float)(LSP - 1) + 1e-5f;
    float sd = sqrtf(var);
    int c = nc & (NC - 1);
    float z = mean * cfc[2 * c] + sd * cfc[2 * c + 1];
    gate[nc] = 1.f / (1.f + __expf(-z));
  }
}

// ---------- s_t[n][l][c] = bf16(x[n][c][l]*gate[n][c]), LDS-tiled transpose --
__global__ __launch_bounds__(256) void k_scale_t(const float* __restrict__ x,
    const float* __restrict__ gate, bf16* __restrict__ s_t) {
  __shared__ bf16 T[64][66];
  int n = blockIdx.z;
  int c0 = blockIdx.y * 64;
  int l0 = blockIdx.x * 64;
  int tid = threadIdx.x;
  int lr = tid & 63, cr = tid >> 6;
#pragma unroll
  for (int k = 0; k < 16; ++k) {
    int c = cr * 16 + k;
    float gv = gate[n * NC + c0 + c];
    float v = x[((size_t)(n * NC + c0 + c)) * LSP + l0 + lr] * gv;
    T[c][lr] = __float2bfloat16(v);
  }
  __syncthreads();
  int cg = tid & 7, lw = tid >> 3;
#pragma unroll
  for (int ps = 0; ps < 2; ++ps) {
    int l = lw + ps * 32;
    unsigned int pk[4];
#pragma unroll
    for (int e = 0; e < 4; ++e)
      pk[e] = (unsigned int)bfu(T[cg * 8 + 2 * e][l]) |
              ((unsigned int)bfu(T[cg * 8 + 2 * e + 1][l]) << 16);
    *(u32x4*)(s_t + ((size_t)n * LSP + l0 + l) * NC + c0 + cg * 8) =
        *(const u32x4*)pk;
  }
}

// ---------- generic NT GEMM body: D[M,N] = A[M,K] * B[N,K]^T + bias ----------
static __device__ __forceinline__ void gemm_nt_body(const bf16* __restrict__ A,
    const bf16* __restrict__ B, const float* __restrict__ bias, int bias_row,
    bf16* __restrict__ D, int Nd, int Kd, int bx) {
  int tn = Nd >> 6;
  int m0 = (bx / tn) * 64, n0 = (bx % tn) * 64;
  int tid = threadIdx.x, w = tid >> 6, lane = tid & 63;
  int lo = lane & 15, g = lane >> 4;
  f32x4 zero = {0.f, 0.f, 0.f, 0.f};
  f32x4 acc[4];
#pragma unroll
  for (int i = 0; i < 4; ++i) acc[i] = zero;
  for (int kc = 0; kc < Kd; kc += 32) {
    short8 bfr = *(const short8*)(B + (size_t)(n0 + w * 16 + lo) * Kd + kc + g * 8);
#pragma unroll
    for (int i = 0; i < 4; ++i) {
      short8 afr = *(const short8*)(A + (size_t)(m0 + 16 * i + lo) * Kd + kc + g * 8);
      acc[i] = MFMA16(afr, bfr, acc[i]);
    }
  }
  int col = n0 + w * 16 + lo;
#pragma unroll
  for (int i = 0; i < 4; ++i)
#pragma unroll
    for (int r = 0; r < 4; ++r) {
      int row = m0 + 16 * i + g * 4 + r;
      float bv = bias_row ? bias[row] : bias[col];
      D[(size_t)row * Nd + col] = __float2bfloat16(acc[i][r] + bv);
    }
}

// ---------- merged projection GEMMs: thph (bx<256) | gT (bx>=256) ----------
__global__ __launch_bounds__(256) void k_gemms(const bf16* __restrict__ s_t,
    const bf16* __restrict__ wbf, const float* __restrict__ bcat,
    const float* __restrict__ g_b, bf16* __restrict__ thph, bf16* __restrict__ gTb) {
  int z = blockIdx.z, bx = blockIdx.x;
  if (bx < 256) {
    gemm_nt_body(s_t + (size_t)z * LSP * NC, wbf, bcat, 0,
                 thph + (size_t)z * LSP * 256, 256, NC, bx);
  } else {
    gemm_nt_body(wbf + 65536, s_t + (size_t)z * LSP * NC, g_b, 1,
                 gTb + (size_t)z * NH * LSP, LSP, NC, bx - 256);
  }
}

// ---------- flash attention: 4 waves x 32 q, KB=32, SPLIT=8 ----------
// XCD-clustered block decode; no P-LDS (shfl-built PV operand); paired-row V.
__global__ __launch_bounds__(256, 4) void k_attn(const bf16* __restrict__ thph,
    const bf16* __restrict__ gT, bf16* __restrict__ Opart, float* __restrict__ ml) {
  __shared__ bf16 Kl[2][KB * NH];    // [j][k] 256B rows, chunk ^= (j&7)      16 KB
  __shared__ bf16 Vl[2][NH * KB];    // paired rows: r=d>>1, 128B, swizzled   16 KB

  // XCD-aware decode: blocks with id%8==x form one L2-coherent class that
  // owns 4 whole (sp,n) pairs -> K/V panels stay resident in that XCD's L2.
  const int id = blockIdx.x;
  const int xcd = id & 7, slot = id >> 3;
  const int pair = xcd * 4 + (slot >> 5);   // 0..31
  const int qb = slot & 31;
  const int sp = pair >> 2, n = pair & 3;

  const int tid = threadIdx.x, w = tid >> 6, lane = tid & 63;
  const int lo = lane & 15, g = lane >> 4;

  const bf16* thn = thph + (size_t)n * LSP * 256;
  const bf16* gv  = gT + (size_t)n * NH * LSP;
  const int q0 = qb * 128 + w * QW;
  const int j0base = sp * (LSP / SPLIT);

  // Q B-frags (loop-invariant, 32 VGPR)
  short8 qf[2][4];
#pragma unroll
  for (int qs = 0; qs < 2; ++qs)
#pragma unroll
    for (int kc = 0; kc < 4; ++kc)
      qf[qs][kc] = *(const short8*)(thn + (size_t)(q0 + qs * 16 + lo) * 256 + kc * 32 + g * 8);

  // staging offsets: source pre-swizzled, LDS dest linear (rule 21)
  int koff[2], voff[2], ldso[2];
#pragma unroll
  for (int i = 0; i < 2; ++i) {
    int ci = i * 256 + tid;
    int kj = ci >> 4, kcc = ci & 15;
    koff[i] = kj * 256 + 128 + ((kcc ^ (kj & 7)) * 8);
    // V paired-row: r = ci>>3 (128B rows), c' = ci&7, c = c'^(r&7)
    int vr = ci >> 3, vcp = ci & 7, vc = vcp ^ (vr & 7);
    int vd = 2 * vr + (vc >> 2), vjb = vc & 3;
    voff[i] = vd * LSP + vjb * 8;
    ldso[i] = ci * 16;
  }

#define STAGE(JT, BUF) do { \
    const bf16* ksrc = thn + (size_t)(j0base + (JT) * KB) * 256; \
    const bf16* vsrc = gv + (j0base + (JT) * KB); \
    char* kdst = (char*)&Kl[BUF][0]; \
    char* vdst = (char*)&Vl[BUF][0]; \
    _Pragma("unroll") \
    for (int i = 0; i < 2; ++i) { \
      GLDS16(ksrc + koff[i], kdst + ldso[i]); \
      GLDS16(vsrc + voff[i], vdst + ldso[i]); \
    } } while (0)

  f32x4 zero = {0.f, 0.f, 0.f, 0.f};
  f32x4 acc[2][8];   // [qs][dc]; D rows = d (g*4+r), col = q = lo
#pragma unroll
  for (int qs = 0; qs < 2; ++qs)
#pragma unroll
    for (int dc = 0; dc < 8; ++dc) acc[qs][dc] = zero;
  float mv[2] = {-1e30f, -1e30f};
  float ls[2] = {0.f, 0.f};

  STAGE(0, 0);

  const int s0l = lo + ((g & 1) << 5);   // shfl src for PV B-frag words 0,1
  const int s1l = s0l + 16;              // words 2,3
  const bool ghi = g >= 2;               // selects src jt = g>>1

  for (int t = 0; t < NTILE; ++t) {
    int cur = t & 1;
    asm volatile("s_waitcnt vmcnt(0)" ::: "memory");
    __builtin_amdgcn_sched_barrier(0);
    __builtin_amdgcn_s_barrier();
    __builtin_amdgcn_sched_barrier(0);
    if (t + 1 < NTILE) STAGE(t + 1, cur ^ 1);

    const char* Kb = (const char*)&Kl[cur][0];
    const char* Vb = (const char*)&Vl[cur][0];

    // S^T: ST[j][q] = sum_k K[j][k] Q[q][k]
    f32x4 st[2][2];
#pragma unroll
    for (int qs = 0; qs < 2; ++qs)
#pragma unroll
      for (int jt = 0; jt < 2; ++jt) st[qs][jt] = zero;
    __builtin_amdgcn_s_setprio(1);
#pragma unroll
    for (int kc = 0; kc < 4; ++kc)
#pragma unroll
      for (int jt = 0; jt < 2; ++jt) {
        short8 ka = *(const short8*)(Kb + (jt * 16 + lo) * 256 + ((kc * 64 + g * 16) ^ ((lo & 7) << 4)));
        st[0][jt] = MFMA16(ka, qf[0][kc], st[0][jt]);
        st[1][jt] = MFMA16(ka, qf[1][kc], st[1][jt]);
      }
    __builtin_amdgcn_s_setprio(0);

    // softmax + in-register P redistribution -> PV B-frags
    short8 bfr[2];
#pragma unroll
    for (int qs = 0; qs < 2; ++qs) {
      float t0 = fmaxf(fmaxf(st[qs][0][0], st[qs][0][1]), fmaxf(st[qs][0][2], st[qs][0][3]));
      float t1 = fmaxf(fmaxf(st[qs][1][0], st[qs][1][1]), fmaxf(st[qs][1][2], st[qs][1][3]));
      float tq = fmaxf(t0, t1);
      tq = fmaxf(tq, __shfl_xor(tq, 16));
      tq = fmaxf(tq, __shfl_xor(tq, 32));

      // defer-max (T13, THR=8); acc col = q = lo -> alpha is lane-local
      if (__any(tq > mv[qs] + 8.f)) {
        float nm = fmaxf(mv[qs], tq);
        float a = __expf(mv[qs] - nm);
        mv[qs] = nm; ls[qs] *= a;
#pragma unroll
        for (int dc = 0; dc < 8; ++dc) {
          acc[qs][dc][0] *= a; acc[qs][dc][1] *= a;
          acc[qs][dc][2] *= a; acc[qs][dc][3] *= a;
        }
      }

      float mm = mv[qs], psum = 0.f;
      float ev[2][4];
#pragma unroll
      for (int jt = 0; jt < 2; ++jt)
#pragma unroll
        for (int r = 0; r < 4; ++r) {
          ev[jt][r] = __expf(st[qs][jt][r] - mm);
          psum += ev[jt][r];
        }
      psum += __shfl_xor(psum, 16);
      psum += __shfl_xor(psum, 32);
      ls[qs] += psum;

      // lane (g,lo) holds P[jt*16+g*4+r][q=lo]; build B-frag P[g*8+m][q=lo]
      unsigned p01_0 = packbf2(ev[0][0], ev[0][1]);
      unsigned p23_0 = packbf2(ev[0][2], ev[0][3]);
      unsigned p01_1 = packbf2(ev[1][0], ev[1][1]);
      unsigned p23_1 = packbf2(ev[1][2], ev[1][3]);
      unsigned a0 = __shfl(p01_0, s0l), b0 = __shfl(p01_1, s0l);
      unsigned a1 = __shfl(p23_0, s0l), b1 = __shfl(p23_1, s0l);
      unsigned a2 = __shfl(p01_0, s1l), b2 = __shfl(p01_1, s1l);
      unsigned a3 = __shfl(p23_0, s1l), b3 = __shfl(p23_1, s1l);
      u32x4 bw;
      bw.x = ghi ? b0 : a0;
      bw.y = ghi ? b1 : a1;
      bw.z = ghi ? b2 : a2;
      bw.w = ghi ? b3 : a3;
      bfr[qs] = __builtin_bit_cast(short8, bw);
    }

    // PV: O = V * P; A-frag = V[d = dc*16+lo][j = g*8..+7] from paired rows
    __builtin_amdgcn_s_setprio(1);
#pragma unroll
    for (int dc = 0; dc < 8; ++dc) {
      int d = dc * 16 + lo;
      int vr = d >> 1;
      int vc = (((d & 1) << 2) + g) ^ (vr & 7);
      short8 vb = *(const short8*)(Vb + vr * 128 + vc * 16);
      acc[0][dc] = MFMA16(vb, bfr[0], acc[0][dc]);
      acc[1][dc] = MFMA16(vb, bfr[1], acc[1][dc]);
    }
    __builtin_amdgcn_s_setprio(0);
  }

  // epilogue: lane holds O[q = qs*16+lo][d = dc*16+g*4+r], unnormalized
  bf16* opb = Opart + ((size_t)(sp * 4 + n) * LSP + q0) * NH;
#pragma unroll
  for (int qs = 0; qs < 2; ++qs)
#pragma unroll
    for (int dc = 0; dc < 8; ++dc) {
      u32x2 pk;
      pk.x = packbf2(acc[qs][dc][0], acc[qs][dc][1]);
      pk.y = packbf2(acc[qs][dc][2], acc[qs][dc][3]);
      *(u32x2*)(opb + (size_t)(qs * 16 + lo) * NH + dc * 16 + g * 4) = pk;
    }
  if (g == 0) {
    float2* mlp = (float2*)ml + (size_t)(sp * 4 + n) * LSP + q0;
#pragma unroll
    for (int qs = 0; qs < 2; ++qs)
      mlp[qs * 16 + lo] = make_float2(mv[qs], ls[qs]);
  }
#undef STAGE
}

// ---------- fused combine + out-proj + residual (512 thr, 8 waves) ----------
__global__ __launch_bounds__(512) void k_final(const bf16* __restrict__ Wo,
    const bf16* __restrict__ Opart, const float* __restrict__ ml,
    const float* __restrict__ x, const float* __restrict__ gate,
    const float* __restrict__ ob, float* __restrict__ out) {
  __shared__ bf16 Ol[64 * NH];   // [l][ch] 256B rows, chunk ^= (l&7)  16 KB
  int n = blockIdx.z;
  int l0 = blockIdx.x * 64;
  int tid = threadIdx.x;

  // ---- combine: Ol[l][ch] = sum_s sc_s * Opart[s][n][l0+l][ch] ----
  {
    int l = tid >> 3, octp = tid & 7;
    float sc[SPLIT];
    float2 m4[SPLIT];
    float mx = -1e30f;
#pragma unroll
    for (int s = 0; s < SPLIT; ++s) {
      m4[s] = ((const float2*)ml)[(size_t)(s * 4 + n) * LSP + l0 + l];
      mx = fmaxf(mx, m4[s].x);
    }
    float den = 0.f;
#pragma unroll
    for (int s = 0; s < SPLIT; ++s) { sc[s] = __expf(m4[s].x - mx); den += m4[s].y * sc[s]; }
    float inv = 1.f / den;
#pragma unroll
    for (int s = 0; s < SPLIT; ++s) sc[s] *= inv;
#pragma unroll
    for (int k = 0; k < 2; ++k) {
      int oct = octp + 8 * k;        // ch base = oct*8
      float o8[8] = {0.f, 0.f, 0.f, 0.f, 0.f, 0.f, 0.f, 0.f};
#pragma unroll
      for (int s = 0; s < SPLIT; ++s) {
        short8 v = *(const short8*)(Opart + ((size_t)(s * 4 + n) * LSP + l0 + l) * NH + oct * 8);
#pragma unroll
        for (int e = 0; e < 8; ++e) o8[e] += sc[s] * bf2f((unsigned short)v[e]);
      }
      u32x4 pk4;
      pk4.x = packbf2(o8[0], o8[1]); pk4.y = packbf2(o8[2], o8[3]);
      pk4.z = packbf2(o8[4], o8[5]); pk4.w = packbf2(o8[6], o8[7]);
      *(u32x4*)((char*)Ol + l * 256 + ((oct * 16) ^ ((l & 7) << 4))) = pk4;
    }
  }
  __syncthreads();

  // ---- GEMM: wave w -> c-range (w&3)*64, l-half (w>>2)*32 ----
  int w = tid >> 6, lane = tid & 63;
  int lo = lane & 15, g = lane >> 4;
  int cb = (w & 3) * 64, lh = (w >> 2) * 32;
  f32x4 zero = {0.f, 0.f, 0.f, 0.f};
  f32x4 acc[4][2];   // [c-tile][l-tile]
#pragma unroll
  for (int i = 0; i < 4; ++i)
#pragma unroll
    for (int j = 0; j < 2; ++j) acc[i][j] = zero;
#pragma unroll
  for (int kc = 0; kc < 4; ++kc) {
    short8 bfr[2];
#pragma unroll
    for (int lt = 0; lt < 2; ++lt) {
      int l = lh + lt * 16 + lo;
      bfr[lt] = *(const short8*)((const char*)Ol + l * 256 + ((kc * 64 + g * 16) ^ ((l & 7) << 4)));
    }
#pragma unroll
    for (int i = 0; i < 4; ++i) {
      short8 afr = *(const short8*)(Wo + (size_t)(cb + 16 * i + lo) * NH + kc * 32 + g * 8);
#pragma unroll
      for (int lt = 0; lt < 2; ++lt)
        acc[i][lt] = MFMA16(afr, bfr[lt], acc[i][lt]);
    }
  }
#pragma unroll
  for (int i = 0; i < 4; ++i)
#pragma unroll
    for (int r = 0; r < 4; ++r) {
      int c = cb + 16 * i + g * 4 + r;
      float obc = ob[c];
      float gc = gate[n * NC + c];
#pragma unroll
      for (int lt = 0; lt < 2; ++lt) {
        int l = l0 + lh + lt * 16 + lo;
        size_t xo = ((size_t)(n * NC + c)) * LSP + l;
        out[xo] = acc[i][lt][r] + obc + x[xo] * gc;
      }
    }
}

extern "C" void kernel_launch(void* const* d_in, const int* in_sizes, int n_in,
                              void* d_out, int out_size, void* d_ws, size_t ws_size,
                              hipStream_t stream) {
  const float* x       = (const float*)d_in[0];
  const float* cfc     = (const float*)d_in[1];
  const float* theta_w = (const float*)d_in[2];
  const float* theta_b = (const float*)d_in[3];
  const float* phi_w   = (const float*)d_in[4];
  const float* phi_b   = (const float*)d_in[5];
  const float* g_w     = (const float*)d_in[6];
  const float* g_b     = (const float*)d_in[7];
  const float* out_w   = (const float*)d_in[8];
  const float* out_b   = (const float*)d_in[9];
  float* out = (float*)d_out;

  char* p = (char*)d_ws;
  auto alloc = [&](size_t bytes) { char* r = p; p += (bytes + 255) & ~(size_t)255; return r; };
  float* gate  = (float*)alloc(4 * NC * sizeof(float));
  bf16* s_t    = (bf16*)alloc((size_t)4 * LSP * NC * 2);          // [n][l][c]
  bf16* thph   = (bf16*)alloc((size_t)4 * LSP * 256 * 2);         // [n][l][th|ph]
  bf16* gTb    = (bf16*)alloc((size_t)4 * NH * LSP * 2);          // [n][o][l]
  bf16* wbf    = (bf16*)alloc((size_t)4 * 32768 * 2);             // thW|phW|gW|outW
  float* bcat  = (float*)alloc(256 * sizeof(float));              // theta_b|phi_b
  bf16* Opart  = (bf16*)alloc((size_t)SPLIT * 4 * LSP * NH * 2);  // [s][n][l][d]
  float* ml    = (float*)alloc((size_t)SPLIT * 4 * LSP * 2 * 4);  // [s][n][l][2]

  k_pre<<<1536, 256, 0, stream>>>(theta_w, phi_w, g_w, out_w, theta_b, phi_b,
                                  wbf, bcat, x, cfc, gate);
  k_scale_t<<<dim3(64, 4, 4), 256, 0, stream>>>(x, gate, s_t);
  k_gemms<<<dim3(384, 1, 4), 256, 0, stream>>>(s_t, wbf, bcat, g_b, thph, gTb);
  k_attn<<<dim3(32 * SPLIT * 4), 256, 0, stream>>>(thph, gTb, Opart, ml);
  k_final<<<dim3(64, 1, 4), 512, 0, stream>>>(wbf + 98304, Opart, ml, x, gate, out_b, out);
}

// Round 9
// 171.435 us; speedup vs baseline: 1.4461x; 1.4461x over previous
//
#include <hip/hip_runtime.h>
#include <hip/hip_bf16.h>

#define LSP 4096   // L = H*W
#define NC  256    // C
#define NH  128    // C/2
#define KB  64     // kv tile
#define QW  32     // q rows per wave
#define SPLIT 4    // kv split factor
#define NTILE ((LSP / SPLIT) / KB)   // 16

typedef __attribute__((ext_vector_type(8))) short short8;
typedef __attribute__((ext_vector_type(4))) float f32x4;
typedef __attribute__((ext_vector_type(4))) unsigned int u32x4;
typedef __attribute__((ext_vector_type(2))) unsigned int u32x2;
typedef __hip_bfloat16 bf16;

#define MFMA16(a,b,c) __builtin_amdgcn_mfma_f32_16x16x32_bf16((a),(b),(c),0,0,0)

typedef __attribute__((address_space(1))) const void gas_t;
typedef __attribute__((address_space(3))) void las_t;
#define GLDS16(g, l) __builtin_amdgcn_global_load_lds((gas_t*)(g), (las_t*)(l), 16, 0, 0)

static __device__ __forceinline__ unsigned short f2bf(float f) {
  bf16 h = __float2bfloat16(f);
  return __builtin_bit_cast(unsigned short, h);
}
static __device__ __forceinline__ unsigned int packbf2(float a, float b) {
  return (unsigned int)f2bf(a) | ((unsigned int)f2bf(b) << 16);
}
static __device__ __forceinline__ float bf2f(unsigned short u) {
  return __builtin_bit_cast(float, (unsigned int)u << 16);
}

// ---------- per (n,c): mean/unbiased-std -> sigmoid gate ----------
__global__ __launch_bounds__(256) void k_stats(const float* __restrict__ x,
    const float* __restrict__ cfc, float* __restrict__ gate) {
  int nc = blockIdx.x;   // n*C + c
  const float4* x4 = (const float4*)(x + (size_t)nc * LSP);
  float s = 0.f, q = 0.f;
  for (int i = threadIdx.x; i < LSP / 4; i += 256) {
    float4 v = x4[i];
    s += v.x + v.y + v.z + v.w;
    q += v.x * v.x + v.y * v.y + v.z * v.z + v.w * v.w;
  }
#pragma unroll
  for (int o = 32; o > 0; o >>= 1) { s += __shfl_xor(s, o); q += __shfl_xor(q, o); }
  __shared__ float rs[4], rq[4];
  int w = threadIdx.x >> 6;
  if ((threadIdx.x & 63) == 0) { rs[w] = s; rq[w] = q; }
  __syncthreads();
  if (threadIdx.x == 0) {
    float S = rs[0] + rs[1] + rs[2] + rs[3];
    float Q = rq[0] + rq[1] + rq[2] + rq[3];
    float mean = S / (float)LSP;
    float var = (Q - S * S / (float)LSP) / (float)(LSP - 1) + 1e-5f;
    float sd = sqrtf(var);
    int c = nc & (NC - 1);
    float z = mean * cfc[2 * c] + sd * cfc[2 * c + 1];
    gate[nc] = 1.f / (1.f + __expf(-z));
  }
}

// ---------- per-n gate-scaled bf16 weights ----------
// wtp[n][256][256] = [thW;phW]*gate_c ; wgn[n][128][256] = gW*gate_c ;
// wob[256][128] = bf16(out_w) ; bcat = theta_b|phi_b
__global__ __launch_bounds__(256) void k_wscale(const float* __restrict__ thw,
    const float* __restrict__ phw, const float* __restrict__ gw,
    const float* __restrict__ ow, const float* __restrict__ tb,
    const float* __restrict__ pb, const float* __restrict__ gate,
    bf16* __restrict__ wtp, bf16* __restrict__ wgn, bf16* __restrict__ wob,
    float* __restrict__ bcat) {
  int b = blockIdx.x;
  if (b < 1536) {
    int i = b * 256 + threadIdx.x;          // 0 .. 393215
    int n = i / 98304;
    int r = i - n * 98304;
    if (r < 65536) {
      int row = r >> 8, c = r & 255;
      float wv = row < 128 ? thw[(row << 8) + c] : phw[((row - 128) << 8) + c];
      wtp[(size_t)n * 65536 + r] = __float2bfloat16(wv * gate[(n << 8) + c]);
    } else {
      int rr = r - 65536;
      int row = rr >> 8, c = rr & 255;
      wgn[(size_t)n * 32768 + rr] = __float2bfloat16(gw[(row << 8) + c] * gate[(n << 8) + c]);
    }
  } else {
    int i2 = (b - 1536) * 256 + threadIdx.x;   // 0..32767
    wob[i2] = __float2bfloat16(ow[i2]);
    if (b == 1536)
      bcat[threadIdx.x] = threadIdx.x < 128 ? tb[threadIdx.x] : pb[threadIdx.x - 128];
  }
}

// ---------- fused projections: per 32-l strip, stage x^T then 2 GEMMs ------
// thph[n][l][o0..255] = sum_c wtp[n][o][c] * x[n][c][l] + bcat[o]
// gT[n][o][l]         = sum_c wgn[n][o][c] * x[n][c][l] + g_b[o]
__global__ __launch_bounds__(256, 2) void k_proj(const float* __restrict__ x,
    const bf16* __restrict__ wtp, const bf16* __restrict__ wgn,
    const float* __restrict__ bcat, const float* __restrict__ g_b,
    bf16* __restrict__ thph, bf16* __restrict__ gTb) {
  __shared__ unsigned int T2[128][34];   // [c-pair][l] packed bf16x2, pad 2
  __shared__ bf16 A[32 * NC];            // [l][c], 16B chunks ^= (l&7)  16 KB
  const int n = blockIdx.y;
  const int l0 = blockIdx.x * 32;
  const int tid = threadIdx.x;

  // phase 1: x[c][l0..l0+31], bf16-pack pairs of c
  {
    int l4 = tid & 7, crow = tid >> 3;    // 8 float4 lanes x 32 c-pairs
#pragma unroll
    for (int p = 0; p < 4; ++p) {
      int cp = p * 32 + crow;
      const float4* xa = (const float4*)(x + ((size_t)(n * NC + 2 * cp)) * LSP + l0);
      const float4* xb = (const float4*)(x + ((size_t)(n * NC + 2 * cp + 1)) * LSP + l0);
      float4 va = xa[l4], vb = xb[l4];
      u32x4 w;
      w.x = packbf2(va.x, vb.x); w.y = packbf2(va.y, vb.y);
      w.z = packbf2(va.z, vb.z); w.w = packbf2(va.w, vb.w);
      *(u32x4*)&T2[cp][l4 * 4] = w;
    }
  }
  __syncthreads();

  // phase 2: repack into A[l][c] with chunk swizzle
  {
    int l = tid >> 3, cc8 = tid & 7;
#pragma unroll
    for (int it = 0; it < 4; ++it) {
      int chunk = cc8 + it * 8;           // 8 c's = 4 pairs
      int cp0 = chunk * 4;
      u32x4 w;
      w.x = T2[cp0 + 0][l]; w.y = T2[cp0 + 1][l];
      w.z = T2[cp0 + 2][l]; w.w = T2[cp0 + 3][l];
      *(u32x4*)((char*)A + l * 512 + ((chunk ^ (l & 7)) * 16)) = w;
    }
  }
  __syncthreads();

  const int w = tid >> 6, lane = tid & 63;
  const int lo = lane & 15, g = lane >> 4;
  f32x4 zero = {0.f, 0.f, 0.f, 0.f};

  // GEMM 1: thph D[l=32][o=256]; wave w covers cols co*64 + w*16
#pragma unroll
  for (int co = 0; co < 4; ++co) {
    int col = co * 64 + w * 16 + lo;
    f32x4 acc[2] = {zero, zero};
#pragma unroll
    for (int kc = 0; kc < 8; ++kc) {
      short8 bfr = *(const short8*)(wtp + (size_t)(n * NC + col) * NC + kc * 32 + g * 8);
#pragma unroll
      for (int i = 0; i < 2; ++i) {
        int l = 16 * i + lo;
        short8 afr = *(const short8*)((const char*)A + l * 512 + (((kc * 4 + g) ^ (l & 7)) * 16));
        acc[i] = MFMA16(afr, bfr, acc[i]);
      }
    }
    float bv = bcat[col];
#pragma unroll
    for (int i = 0; i < 2; ++i)
#pragma unroll
      for (int r = 0; r < 4; ++r) {
        int l = 16 * i + g * 4 + r;
        thph[(size_t)n * LSP * NC + (size_t)(l0 + l) * NC + col] =
            __float2bfloat16(acc[i][r] + bv);
      }
  }

  // GEMM 2: gT D[o=128][l=32]; wave w: l-tile (w&1), o-half (w>>1)*64
  {
    int lt = w & 1, oh = w >> 1;
    int col = lt * 16 + lo;               // l index
    f32x4 acc[4] = {zero, zero, zero, zero};
#pragma unroll
    for (int kc = 0; kc < 8; ++kc) {
      short8 bfr = *(const short8*)((const char*)A + col * 512 + (((kc * 4 + g) ^ (col & 7)) * 16));
#pragma unroll
      for (int i = 0; i < 4; ++i) {
        short8 afr = *(const short8*)(wgn + (size_t)n * 32768 +
                                      (size_t)(oh * 64 + 16 * i + lo) * NC + kc * 32 + g * 8);
        acc[i] = MFMA16(afr, bfr, acc[i]);
      }
    }
#pragma unroll
    for (int i = 0; i < 4; ++i)
#pragma unroll
      for (int r = 0; r < 4; ++r) {
        int o = oh * 64 + 16 * i + g * 4 + r;
        gTb[(size_t)n * NH * LSP + (size_t)o * LSP + l0 + col] =
            __float2bfloat16(acc[i][r] + g_b[o]);
      }
  }
}

// ---------- flash attention: R2-proven shape + XCD decode ----------
// 4 waves x 32 q = 128 q/block; KB=64; SPLIT=4; 80 KB LDS -> 2 blocks/CU.
__global__ __launch_bounds__(256, 2) void k_attn(const bf16* __restrict__ thph,
    const bf16* __restrict__ gT, bf16* __restrict__ Opart, float* __restrict__ ml) {
  __shared__ bf16 Kl[2][KB * NH];    // [j][k] 256B rows, chunk ^= (j&7)      32 KB
  __shared__ bf16 Vl[2][NH * KB];    // [d][j] 128B rows, chunk ^= (d&7)      32 KB
  __shared__ bf16 Pl[4][QW * KB];    // per-wave [q][j] 128B rows, ^(q&7)     16 KB

  // XCD decode: class id&7 owns 2 whole (sp,n) pairs -> 1 MB K/V per XCD L2.
  const int id = blockIdx.x;
  const int xcd = id & 7, slot = id >> 3;
  const int pair = xcd * 2 + (slot >> 5);   // 0..15
  const int qb = slot & 31;
  const int sp = pair >> 2, n = pair & 3;

  const int tid = threadIdx.x, w = tid >> 6, lane = tid & 63;
  const int lo = lane & 15, g = lane >> 4;
  const int swz = (lo & 7) << 4;

  const bf16* thn = thph + (size_t)n * LSP * 256;
  const bf16* gv  = gT + (size_t)n * NH * LSP;
  const int q0 = qb * 128 + w * QW;
  const int j0base = sp * (LSP / SPLIT);

  short8 qf[2][4];
#pragma unroll
  for (int qs = 0; qs < 2; ++qs)
#pragma unroll
    for (int kc = 0; kc < 4; ++kc)
      qf[qs][kc] = *(const short8*)(thn + (size_t)(q0 + qs * 16 + lo) * 256 + kc * 32 + g * 8);

  size_t koff[4], voff[4];
  int ldso[4];
#pragma unroll
  for (int i = 0; i < 4; ++i) {
    int ci = i * 256 + tid;
    int kj = ci >> 4, kcc = ci & 15;
    koff[i] = (size_t)kj * 256 + 128 + ((kcc ^ (kj & 7)) * 8);
    int vd = ci >> 3, vc2 = ci & 7;
    voff[i] = (size_t)vd * LSP + ((vc2 ^ (vd & 7)) * 8);
    ldso[i] = ci * 16;
  }

#define STAGE(JT, BUF) do { \
    const bf16* ksrc = thn + (size_t)(j0base + (JT) * KB) * 256; \
    const bf16* vsrc = gv + (j0base + (JT) * KB); \
    char* kdst = (char*)&Kl[BUF][0]; \
    char* vdst = (char*)&Vl[BUF][0]; \
    _Pragma("unroll") \
    for (int i = 0; i < 4; ++i) { \
      GLDS16(ksrc + koff[i], kdst + ldso[i]); \
      GLDS16(vsrc + voff[i], vdst + ldso[i]); \
    } } while (0)

  f32x4 zero = {0.f, 0.f, 0.f, 0.f};
  f32x4 acc[2][8];
#pragma unroll
  for (int qs = 0; qs < 2; ++qs)
#pragma unroll
    for (int dc = 0; dc < 8; ++dc) acc[qs][dc] = zero;
  float mv[2] = {-1e30f, -1e30f};
  float ls[2] = {0.f, 0.f};

  STAGE(0, 0);
  __syncthreads();

  char* pwb = (char*)&Pl[w][0];

  for (int t = 0; t < NTILE; ++t) {
    int cur = t & 1;
    if (t + 1 < NTILE) STAGE(t + 1, cur ^ 1);  // issue early; drained at barrier
    const char* Kb = (const char*)&Kl[cur][0];
    const char* Vb = (const char*)&Vl[cur][0];

    // S^T: ST[j][q] = sum_k K[j][k] Q[q][k]; K-frag shared across both q-sets
    f32x4 st[2][4];
#pragma unroll
    for (int qs = 0; qs < 2; ++qs)
#pragma unroll
      for (int jt = 0; jt < 4; ++jt) st[qs][jt] = zero;
    __builtin_amdgcn_s_setprio(1);
#pragma unroll
    for (int kc = 0; kc < 4; ++kc) {
      int kb = (kc * 64 + g * 16) ^ swz;
#pragma unroll
      for (int jt = 0; jt < 4; ++jt) {
        short8 ka = *(const short8*)(Kb + (jt * 16 + lo) * 256 + kb);
        st[0][jt] = MFMA16(ka, qf[0][kc], st[0][jt]);
        st[1][jt] = MFMA16(ka, qf[1][kc], st[1][jt]);
      }
    }
    __builtin_amdgcn_s_setprio(0);

#pragma unroll
    for (int qs = 0; qs < 2; ++qs) {
      float t0 = fmaxf(fmaxf(st[qs][0][0], st[qs][0][1]), fmaxf(st[qs][0][2], st[qs][0][3]));
      float t1 = fmaxf(fmaxf(st[qs][1][0], st[qs][1][1]), fmaxf(st[qs][1][2], st[qs][1][3]));
      float t2 = fmaxf(fmaxf(st[qs][2][0], st[qs][2][1]), fmaxf(st[qs][2][2], st[qs][2][3]));
      float t3 = fmaxf(fmaxf(st[qs][3][0], st[qs][3][1]), fmaxf(st[qs][3][2], st[qs][3][3]));
      float tq = fmaxf(fmaxf(t0, t1), fmaxf(t2, t3));
      tq = fmaxf(tq, __shfl_xor(tq, 16));
      tq = fmaxf(tq, __shfl_xor(tq, 32));

      // defer-max (T13, THR=8)
      if (__any(tq > mv[qs] + 8.f)) {
        float nm = fmaxf(mv[qs], tq);
        float a = __expf(mv[qs] - nm);
        mv[qs] = nm; ls[qs] *= a;
#pragma unroll
        for (int r = 0; r < 4; ++r) {
          float b = __shfl(a, g * 4 + r);
#pragma unroll
          for (int dc = 0; dc < 8; ++dc) acc[qs][dc][r] *= b;
        }
      }

      float mm = mv[qs], psum = 0.f;
      int rowb = (qs * 16 + lo) * 128;
#pragma unroll
      for (int jt = 0; jt < 4; ++jt) {
        float e0 = __expf(st[qs][jt][0] - mm);
        float e1 = __expf(st[qs][jt][1] - mm);
        float e2 = __expf(st[qs][jt][2] - mm);
        float e3 = __expf(st[qs][jt][3] - mm);
        psum += (e0 + e1) + (e2 + e3);
        u32x2 pk;
        pk.x = packbf2(e0, e1);
        pk.y = packbf2(e2, e3);
        *(u32x2*)(pwb + rowb + ((jt * 32 + g * 8) ^ swz)) = pk;
      }
      psum += __shfl_xor(psum, 16);
      psum += __shfl_xor(psum, 32);
      ls[qs] += psum;
    }

    asm volatile("" ::: "memory");  // order P ds_writes before ds_reads
#pragma unroll
    for (int kc2 = 0; kc2 < 2; ++kc2) {
      int kbb = kc2 * 64 + g * 16;
      short8 pa0 = *(const short8*)(pwb + lo * 128 + (kbb ^ swz));
      short8 pa1 = *(const short8*)(pwb + (16 + lo) * 128 + (kbb ^ swz));
      __builtin_amdgcn_s_setprio(1);
#pragma unroll
      for (int dc = 0; dc < 8; ++dc) {
        int d = dc * 16 + lo;
        short8 vb = *(const short8*)(Vb + d * 128 + (kbb ^ ((d & 7) << 4)));
        acc[0][dc] = MFMA16(pa0, vb, acc[0][dc]);
        acc[1][dc] = MFMA16(pa1, vb, acc[1][dc]);
      }
      __builtin_amdgcn_s_setprio(0);
    }
    __syncthreads();  // prefetch drained; both buffers consistent
  }

  bf16* opb = Opart + ((size_t)(sp * 4 + n) * LSP + q0) * NH;
#pragma unroll
  for (int qs = 0; qs < 2; ++qs)
#pragma unroll
    for (int dc = 0; dc < 8; ++dc)
#pragma unroll
      for (int r = 0; r < 4; ++r)
        opb[(size_t)(qs * 16 + g * 4 + r) * NH + dc * 16 + lo] =
            __float2bfloat16(acc[qs][dc][r]);
  if (g == 0) {
    float2* mlp = (float2*)ml + (size_t)(sp * 4 + n) * LSP + q0;
#pragma unroll
    for (int qs = 0; qs < 2; ++qs)
      mlp[qs * 16 + lo] = make_float2(mv[qs], ls[qs]);
  }
#undef STAGE
}

// ---------- fused combine + out-proj + residual (512 thr, 8 waves) ----------
__global__ __launch_bounds__(512) void k_final(const bf16* __restrict__ Wo,
    const bf16* __restrict__ Opart, const float* __restrict__ ml,
    const float* __restrict__ x, const float* __restrict__ gate,
    const float* __restrict__ ob, float* __restrict__ out) {
  __shared__ bf16 Ol[64 * NH];   // [l][ch] 256B rows, chunk ^= (l&7)  16 KB
  int n = blockIdx.z;
  int l0 = blockIdx.x * 64;
  int tid = threadIdx.x;

  {
    int l = tid >> 3, octp = tid & 7;
    float sc[SPLIT];
    float2 m4[SPLIT];
    float mx = -1e30f;
#pragma unroll
    for (int s = 0; s < SPLIT; ++s) {
      m4[s] = ((const float2*)ml)[(size_t)(s * 4 + n) * LSP + l0 + l];
      mx = fmaxf(mx, m4[s].x);
    }
    float den = 0.f;
#pragma unroll
    for (int s = 0; s < SPLIT; ++s) { sc[s] = __expf(m4[s].x - mx); den += m4[s].y * sc[s]; }
    float inv = 1.f / den;
#pragma unroll
    for (int s = 0; s < SPLIT; ++s) sc[s] *= inv;
#pragma unroll
    for (int k = 0; k < 2; ++k) {
      int oct = octp + 8 * k;
      float o8[8] = {0.f, 0.f, 0.f, 0.f, 0.f, 0.f, 0.f, 0.f};
#pragma unroll
      for (int s = 0; s < SPLIT; ++s) {
        short8 v = *(const short8*)(Opart + ((size_t)(s * 4 + n) * LSP + l0 + l) * NH + oct * 8);
#pragma unroll
        for (int e = 0; e < 8; ++e) o8[e] += sc[s] * bf2f((unsigned short)v[e]);
      }
      u32x4 pk4;
      pk4.x = packbf2(o8[0], o8[1]); pk4.y = packbf2(o8[2], o8[3]);
      pk4.z = packbf2(o8[4], o8[5]); pk4.w = packbf2(o8[6], o8[7]);
      *(u32x4*)((char*)Ol + l * 256 + ((oct * 16) ^ ((l & 7) << 4))) = pk4;
    }
  }
  __syncthreads();

  int w = tid >> 6, lane = tid & 63;
  int lo = lane & 15, g = lane >> 4;
  int cb = (w & 3) * 64, lh = (w >> 2) * 32;
  f32x4 zero = {0.f, 0.f, 0.f, 0.f};
  f32x4 acc[4][2];
#pragma unroll
  for (int i = 0; i < 4; ++i)
#pragma unroll
    for (int j = 0; j < 2; ++j) acc[i][j] = zero;
#pragma unroll
  for (int kc = 0; kc < 4; ++kc) {
    short8 bfr[2];
#pragma unroll
    for (int lt = 0; lt < 2; ++lt) {
      int l = lh + lt * 16 + lo;
      bfr[lt] = *(const short8*)((const char*)Ol + l * 256 + ((kc * 64 + g * 16) ^ ((l & 7) << 4)));
    }
#pragma unroll
    for (int i = 0; i < 4; ++i) {
      short8 afr = *(const short8*)(Wo + (size_t)(cb + 16 * i + lo) * NH + kc * 32 + g * 8);
#pragma unroll
      for (int lt = 0; lt < 2; ++lt)
        acc[i][lt] = MFMA16(afr, bfr[lt], acc[i][lt]);
    }
  }
#pragma unroll
  for (int i = 0; i < 4; ++i)
#pragma unroll
    for (int r = 0; r < 4; ++r) {
      int c = cb + 16 * i + g * 4 + r;
      float obc = ob[c];
      float gc = gate[n * NC + c];
#pragma unroll
      for (int lt = 0; lt < 2; ++lt) {
        int l = l0 + lh + lt * 16 + lo;
        size_t xo = ((size_t)(n * NC + c)) * LSP + l;
        out[xo] = acc[i][lt][r] + obc + x[xo] * gc;
      }
    }
}

extern "C" void kernel_launch(void* const* d_in, const int* in_sizes, int n_in,
                              void* d_out, int out_size, void* d_ws, size_t ws_size,
                              hipStream_t stream) {
  const float* x       = (const float*)d_in[0];
  const float* cfc     = (const float*)d_in[1];
  const float* theta_w = (const float*)d_in[2];
  const float* theta_b = (const float*)d_in[3];
  const float* phi_w   = (const float*)d_in[4];
  const float* phi_b   = (const float*)d_in[5];
  const float* g_w     = (const float*)d_in[6];
  const float* g_b     = (const float*)d_in[7];
  const float* out_w   = (const float*)d_in[8];
  const float* out_b   = (const float*)d_in[9];
  float* out = (float*)d_out;

  char* p = (char*)d_ws;
  auto alloc = [&](size_t bytes) { char* r = p; p += (bytes + 255) & ~(size_t)255; return r; };
  float* gate  = (float*)alloc(4 * NC * sizeof(float));
  bf16* thph   = (bf16*)alloc((size_t)4 * LSP * 256 * 2);         // [n][l][th|ph]
  bf16* gTb    = (bf16*)alloc((size_t)4 * NH * LSP * 2);          // [n][o][l]
  bf16* wtp    = (bf16*)alloc((size_t)4 * 65536 * 2);             // [n][256][256]
  bf16* wgn    = (bf16*)alloc((size_t)4 * 32768 * 2);             // [n][128][256]
  bf16* wob    = (bf16*)alloc((size_t)32768 * 2);                 // [256][128]
  float* bcat  = (float*)alloc(256 * sizeof(float));
  bf16* Opart  = (bf16*)alloc((size_t)SPLIT * 4 * LSP * NH * 2);  // [s][n][l][d]
  float* ml    = (float*)alloc((size_t)SPLIT * 4 * LSP * 2 * 4);  // [s][n][l][2]

  k_stats<<<4 * NC, 256, 0, stream>>>(x, cfc, gate);
  k_wscale<<<1664, 256, 0, stream>>>(theta_w, phi_w, g_w, out_w, theta_b, phi_b,
                                     gate, wtp, wgn, wob, bcat);
  k_proj<<<dim3(LSP / 32, 4), 256, 0, stream>>>(x, wtp, wgn, bcat, g_b, thph, gTb);
  k_attn<<<dim3(32 * SPLIT * 4), 256, 0, stream>>>(thph, gTb, Opart, ml);
  k_final<<<dim3(64, 1, 4), 512, 0, stream>>>(wob, Opart, ml, x, gate, out_b, out);
}